// Round 8
// baseline (91627.838 us; speedup 1.0000x reference)
//
#include <hip/hip_runtime.h>
#include <cstddef>

// ---------------------------------------------------------------------------
// 3-layer LSTM (1->32->32->3), T=200000 sequential steps.
// 4-wave DECOUPLED systolic pipeline on one CU -- NO per-step barrier.
//   wave 0: layer 0            h0(t)
//   wave 1: layer 1 U-part     U(t)=Wih1*h0(t)+b1A
//   wave 2: layer 1 V-part     V(t)=Whh1*h1(t-1); cell; h1(t)
//   wave 3: layer 2 + output   out(t); also stages x chunks
// Edges are ring buffers (depth 8) in LDS with monotonic iteration counters:
//   producer: data ds_writes; s_waitcnt lgkmcnt(0); volatile counter = t+1
//   consumer: cached-counter check, volatile spin only if insufficient
// Counter publish happens only after lgkmcnt(0) drain -> counter-visible
// implies data-committed (no DS ordering assumption needed). Credit
// counters (consumer progress) prevent ring overwrite; depth 8 >> pipeline
// depth 3 so steady state has zero spins.
//
// R7: cross-half exchange back to __shfl_xor(.,32) -- R6's permlane32_swap
// lane mapping was the suspected mis-step (50/50 doc ambiguity); all other
// arithmetic is bit-identical to the PASSING R5 kernel.
// ---------------------------------------------------------------------------

#define XCH 256  // x chunk elements (power of two)

// counter indices
#define H0CNT   0
#define UCNT    1
#define H1CNT   2
#define W1DONE  3
#define W2UDONE 4
#define W3DONE  5
#define XCNT    6

typedef float f32x2 __attribute__((ext_vector_type(2)));

__device__ __forceinline__ f32x2 pk_fma(f32x2 a, f32x2 b, f32x2 c) {
    f32x2 d;
    asm("v_pk_fma_f32 %0, %1, %2, %3" : "=v"(d) : "v"(a), "v"(b), "v"(c));
    return d;
}
__device__ __forceinline__ f32x2 lds_ld2(const float* p) {
    f32x2 v; __builtin_memcpy(&v, p, sizeof(f32x2)); return v;
}

__device__ __forceinline__ float v_exp2(float x) {
    float r; asm("v_exp_f32 %0, %1" : "=v"(r) : "v"(x)); return r;
}
__device__ __forceinline__ float v_rcp(float x) {
    float r; asm("v_rcp_f32 %0, %1" : "=v"(r) : "v"(x)); return r;
}
// act = m / (1 + exp(z)) + a0, residual-compensated v_exp + Newton v_rcp.
__device__ __forceinline__ float fast_gate(float z, float m, float a0) {
    const float L2E    = 1.44269502162933349609375f;
    const float L2E_LO = 1.9259629911e-8f;
    const float LN2    = 0.69314718055994530942f;
    const float t  = z * L2E;
    const float r  = fmaf(z, L2E, -t);
    const float dt = fmaf(z, L2E_LO, r);
    const float e0 = v_exp2(t);
    const float e  = fmaf(e0, dt * LN2, e0);
    const float den = 1.0f + e;
    const float r0 = v_rcp(den);
    const float er = fmaf(-den, r0, 1.0f);
    const float r1 = fmaf(r0, er, r0);
    return fmaf(m, r1, a0);
}
__device__ __forceinline__ float fast_tanh(float c) {
    return fast_gate(-2.0f * c, 2.0f, -1.0f);
}

// cross-half exchange: lane^32's value (R5-proven path).
__device__ __forceinline__ float swap_half(float v) {
    return __shfl_xor(v, 32);
}

// drain LDS ops + compiler fence (producer: before counter publish)
__device__ __forceinline__ void fence_lds() {
    asm volatile("s_waitcnt lgkmcnt(0)" ::: "memory");
}
// consumer-side: spin until *c >= need (cached); compiler fence on exit
__device__ __forceinline__ void spin_ge(volatile int* c, int need, int& cache) {
    while (cache < need) cache = *c;
    asm volatile("" ::: "memory");
}

__global__ __launch_bounds__(256, 1)
void lstm3_ring_kernel(const float* __restrict__ x,
                       const float* __restrict__ Wih0, const float* __restrict__ Whh0,
                       const float* __restrict__ bih0, const float* __restrict__ bhh0,
                       const float* __restrict__ Wih1, const float* __restrict__ Whh1,
                       const float* __restrict__ bih1, const float* __restrict__ bhh1,
                       const float* __restrict__ pre_h0, const float* __restrict__ pre_c0,
                       const float* __restrict__ Wih2, const float* __restrict__ Whh2,
                       const float* __restrict__ bih2, const float* __restrict__ bhh2,
                       const float* __restrict__ post_h0, const float* __restrict__ post_c0,
                       float* __restrict__ out, int T)
{
    const int tid = threadIdx.x;
    const int w   = tid >> 6;     // 0=L0, 1=L1-U, 2=L1-V, 3=L2+x
    const int l   = tid & 63;

    __shared__ __align__(16) float h0r[8][32];    // h0 ring
    __shared__ __align__(16) float h1r[8][32];    // h1 ring
    __shared__ __align__(16) float ur[8][128];    // U ring
    __shared__ __align__(16) float xr[4][XCH];    // x chunk ring
    __shared__ volatile int cnts[8];

    if (tid == 0) {
        cnts[H0CNT] = 0; cnts[UCNT] = 0; cnts[H1CNT] = 0;
        cnts[W1DONE] = 0; cnts[W2UDONE] = 0; cnts[W3DONE] = 0;
    }

    if (w == 0) {
        // =============== wave 0: layer 0 (1 -> 32) ===============
        const int gA = l, gB = l + 64;
        const float wx0A = Wih0[gA];
        const float wx0B = Wih0[gB];
        const float b0A  = bih0[gA] + bhh0[gA];
        const float b0B  = bih0[gB] + bhh0[gB];
        f32x2 wA2[16], wB2[16];
#pragma unroll
        for (int r = 0; r < 16; ++r) {
            wA2[r][0] = Whh0[gA * 32 + 2 * r]; wA2[r][1] = Whh0[gA * 32 + 2 * r + 1];
            wB2[r][0] = Whh0[gB * 32 + 2 * r]; wB2[r][1] = Whh0[gB * 32 + 2 * r + 1];
        }
        const float kB  = (l < 32) ? -2.0f : -1.0f;
        const float mB  = (l < 32) ?  2.0f :  1.0f;
        const float a0B = (l < 32) ? -1.0f :  0.0f;

        float c0 = 0.0f;
        if (l < 32) { c0 = pre_c0[l]; h0r[7][l] = pre_h0[l]; }
        __syncthreads();

        int c_x = 0, c_w1 = 0;
        for (int t = 0; t < T; ++t) {
            if ((t & (XCH - 1)) == 0)
                spin_ge(&cnts[XCNT], (t >> 8) + 1, c_x);
            if (t >= 8)
                spin_ge(&cnts[W1DONE], t - 7, c_w1);
            const float xn = xr[(t >> 8) & 3][t & (XCH - 1)];
            const float* hp = h0r[(t + 7) & 7];   // h0(t-1)
            f32x2 aA0, aA1, aB0, aB1;
            aA0[0] = fmaf(xn, wx0A, b0A); aA0[1] = 0.0f;
            aA1[0] = 0.0f;                aA1[1] = 0.0f;
            aB0[0] = fmaf(xn, wx0B, b0B); aB0[1] = 0.0f;
            aB1[0] = 0.0f;                aB1[1] = 0.0f;
#pragma unroll
            for (int q = 0; q < 8; ++q) {
                const f32x2 h01 = lds_ld2(&hp[q * 4]);
                const f32x2 h23 = lds_ld2(&hp[q * 4 + 2]);
                aA0 = pk_fma(h01, wA2[2 * q],     aA0);
                aA1 = pk_fma(h23, wA2[2 * q + 1], aA1);
                aB0 = pk_fma(h01, wB2[2 * q],     aB0);
                aB1 = pk_fma(h23, wB2[2 * q + 1], aB1);
            }
            const float sA = (aA0[0] + aA0[1]) + (aA1[0] + aA1[1]);
            const float sB = (aB0[0] + aB0[1]) + (aB1[0] + aB1[1]);
            const float actA = fast_gate(-sA, 1.0f, 0.0f);
            const float actB = fast_gate(kB * sB, mB, a0B);
            const float foA = swap_half(actA);    // lanes<32: f
            const float foB = swap_half(actB);    // lanes<32: o
            if (l < 32) {
                c0 = fmaf(foA, c0, actA * actB);
                h0r[t & 7][l] = foB * fast_tanh(c0);
            }
            fence_lds();
            if (l == 0) cnts[H0CNT] = t + 1;
        }
    } else if (w == 1) {
        // ========= wave 1: layer 1 U = Wih1 * h0(t) =========
        const int gA = l, gB = l + 64;
        const float b1A = bih1[gA] + bhh1[gA];
        f32x2 wA2[16], wB2[16];
#pragma unroll
        for (int r = 0; r < 16; ++r) {
            wA2[r][0] = Wih1[gA * 32 + 2 * r]; wA2[r][1] = Wih1[gA * 32 + 2 * r + 1];
            wB2[r][0] = Wih1[gB * 32 + 2 * r]; wB2[r][1] = Wih1[gB * 32 + 2 * r + 1];
        }
        __syncthreads();

        int c_h0 = 0, c_w2u = 0;
        for (int t = 0; t < T; ++t) {
            spin_ge(&cnts[H0CNT], t + 1, c_h0);
            if (t >= 8)
                spin_ge(&cnts[W2UDONE], t - 7, c_w2u);
            const float* hp = h0r[t & 7];         // h0(t)
            f32x2 uA0, uA1, uB0, uB1;
            uA0[0] = b1A;  uA0[1] = 0.0f;
            uA1[0] = 0.0f; uA1[1] = 0.0f;
            uB0[0] = 0.0f; uB0[1] = 0.0f;
            uB1[0] = 0.0f; uB1[1] = 0.0f;
#pragma unroll
            for (int q = 0; q < 8; ++q) {
                const f32x2 h01 = lds_ld2(&hp[q * 4]);
                const f32x2 h23 = lds_ld2(&hp[q * 4 + 2]);
                uA0 = pk_fma(h01, wA2[2 * q],     uA0);
                uA1 = pk_fma(h23, wA2[2 * q + 1], uA1);
                uB0 = pk_fma(h01, wB2[2 * q],     uB0);
                uB1 = pk_fma(h23, wB2[2 * q + 1], uB1);
            }
            ur[t & 7][l]      = (uA0[0] + uA0[1]) + (uA1[0] + uA1[1]);
            ur[t & 7][l + 64] = (uB0[0] + uB0[1]) + (uB1[0] + uB1[1]);
            fence_lds();
            if (l < 2) cnts[l ? W1DONE : UCNT] = t + 1;
        }
    } else if (w == 2) {
        // ===== wave 2: layer 1 V + cell update (the recurrence pacer) =====
        const int gA = l, gB = l + 64;
        const float b1B = bih1[gB] + bhh1[gB];
        f32x2 wA2[16], wB2[16];
#pragma unroll
        for (int r = 0; r < 16; ++r) {
            wA2[r][0] = Whh1[gA * 32 + 2 * r]; wA2[r][1] = Whh1[gA * 32 + 2 * r + 1];
            wB2[r][0] = Whh1[gB * 32 + 2 * r]; wB2[r][1] = Whh1[gB * 32 + 2 * r + 1];
        }
        const float kB  = (l < 32) ? -2.0f : -1.0f;
        const float mB  = (l < 32) ?  2.0f :  1.0f;
        const float a0B = (l < 32) ? -1.0f :  0.0f;

        float c1 = 0.0f;
        if (l < 32) { c1 = pre_c0[32 + l]; h1r[7][l] = pre_h0[32 + l]; }
        __syncthreads();

        int c_u = 0, c_w3 = 0;
        for (int t = 0; t < T; ++t) {
            spin_ge(&cnts[UCNT], t + 1, c_u);
            if (t >= 8)
                spin_ge(&cnts[W3DONE], t - 7, c_w3);
            const float* up = ur[t & 7];
            const float UA = up[l];               // issue early
            const float UB = up[l + 64];
            const float* gp = h1r[(t + 7) & 7];   // h1(t-1), own prev write
            f32x2 vA0, vA1, vB0, vB1;
            vA0[0] = 0.0f; vA0[1] = 0.0f;
            vA1[0] = 0.0f; vA1[1] = 0.0f;
            vB0[0] = b1B;  vB0[1] = 0.0f;
            vB1[0] = 0.0f; vB1[1] = 0.0f;
#pragma unroll
            for (int q = 0; q < 8; ++q) {
                const f32x2 g01 = lds_ld2(&gp[q * 4]);
                const f32x2 g23 = lds_ld2(&gp[q * 4 + 2]);
                vA0 = pk_fma(g01, wA2[2 * q],     vA0);
                vA1 = pk_fma(g23, wA2[2 * q + 1], vA1);
                vB0 = pk_fma(g01, wB2[2 * q],     vB0);
                vB1 = pk_fma(g23, wB2[2 * q + 1], vB1);
            }
            const float sA = UA + ((vA0[0] + vA0[1]) + (vA1[0] + vA1[1]));
            const float sB = UB + ((vB0[0] + vB0[1]) + (vB1[0] + vB1[1]));
            const float actA = fast_gate(-sA, 1.0f, 0.0f);
            const float actB = fast_gate(kB * sB, mB, a0B);
            const float foA = swap_half(actA);
            const float foB = swap_half(actB);
            if (l < 32) {
                c1 = fmaf(foA, c1, actA * actB);
                h1r[t & 7][l] = foB * fast_tanh(c1);
            }
            fence_lds();
            if (l < 2) cnts[l ? W2UDONE : H1CNT] = t + 1;
        }
    } else {
        // ===== wave 3: layer 2 (32 -> 3) + output; x chunk staging =====
        const int g2 = (l < 48) ? (l >> 2) : 0;
        const int p  = l & 3;
        f32x2 w2p[4];
#pragma unroll
        for (int r = 0; r < 4; ++r) {
            w2p[r][0] = Wih2[g2 * 32 + p * 8 + 2 * r];
            w2p[r][1] = Wih2[g2 * 32 + p * 8 + 2 * r + 1];
        }
        float wr2[3];
#pragma unroll
        for (int r = 0; r < 3; ++r) wr2[r] = Whh2[g2 * 3 + r];
        const float b2 = bih2[g2] + bhh2[g2];
        const bool  g2tanh = (g2 >= 6 && g2 <= 8);
        const float k2  = g2tanh ? -2.0f : -1.0f;
        const float m2  = g2tanh ?  2.0f :  1.0f;
        const float a02 = g2tanh ? -1.0f :  0.0f;

        float c2 = 0.0f;
        if (l < 3) c2 = post_c0[l];
        float h2p0 = post_h0[0], h2p1 = post_h0[1], h2p2 = post_h0[2];
        float h2v = 0.0f;

        // stage x chunk 0
        {
            const int i0 = 4 * l;
            if (i0 < T) {
                const float* xp = x + i0;
                float4 v;
                v.x = xp[0] / 25.0f;
                v.y = (i0 + 1 < T) ? xp[1] / 25.0f : 0.0f;
                v.z = (i0 + 2 < T) ? xp[2] / 25.0f : 0.0f;
                v.w = (i0 + 3 < T) ? xp[3] / 25.0f : 0.0f;
                __builtin_memcpy(&xr[0][i0], &v, sizeof(float4));
            }
        }
        fence_lds();
        if (l == 0) cnts[XCNT] = 1;
        __syncthreads();

        int c_h1 = 0, c_h0c = 0;
        for (int t = 0; t < T; ++t) {
            if ((t & (XCH - 1)) == 0) {
                const int c = (t >> 8) + 1;       // next chunk to stage
                const int base = c * XCH;
                if (base < T) {
                    if (c >= 4)                    // slot c&3 held chunk c-4
                        spin_ge(&cnts[H0CNT], (c - 3) * XCH, c_h0c);
                    const int i0 = base + 4 * l;
                    if (i0 < T) {
                        const float* xp = x + i0;
                        float4 v;
                        v.x = xp[0] / 25.0f;
                        v.y = (i0 + 1 < T) ? xp[1] / 25.0f : 0.0f;
                        v.z = (i0 + 2 < T) ? xp[2] / 25.0f : 0.0f;
                        v.w = (i0 + 3 < T) ? xp[3] / 25.0f : 0.0f;
                        __builtin_memcpy(&xr[c & 3][4 * l], &v, sizeof(float4));
                    }
                    fence_lds();
                    if (l == 0) cnts[XCNT] = c + 1;
                }
            }
            spin_ge(&cnts[H1CNT], t + 1, c_h1);
            const float* hp = h1r[t & 7];         // h1(t)
            f32x2 acc; acc[0] = 0.0f; acc[1] = 0.0f;
            {
                const f32x2 a01 = lds_ld2(&hp[p * 8 + 0]);
                const f32x2 a23 = lds_ld2(&hp[p * 8 + 2]);
                const f32x2 b01 = lds_ld2(&hp[p * 8 + 4]);
                const f32x2 b23 = lds_ld2(&hp[p * 8 + 6]);
                acc = pk_fma(a01, w2p[0], acc);
                acc = pk_fma(a23, w2p[1], acc);
                acc = pk_fma(b01, w2p[2], acc);
                acc = pk_fma(b23, w2p[3], acc);
            }
            float a2 = acc[0] + acc[1];
            a2 += __shfl_xor(a2, 1);
            a2 += __shfl_xor(a2, 2);
            const float rec = fmaf(wr2[2], h2p2,
                              fmaf(wr2[1], h2p1,
                              fmaf(wr2[0], h2p0, b2)));
            a2 += rec;
            const float act2 = fast_gate(k2 * a2, m2, a02);
            const int j = (l < 3) ? l : 0;
            const float i2  = __shfl(act2,  4 * j);
            const float f2  = __shfl(act2, 12 + 4 * j);
            const float g2v = __shfl(act2, 24 + 4 * j);
            const float o2  = __shfl(act2, 36 + 4 * j);
            if (l < 3) {
                c2 = fmaf(f2, c2, i2 * g2v);
                h2v = o2 * fast_tanh(c2);
                out[(size_t)t * 3 + l] = h2v;     // fire-and-forget
            }
            h2p0 = __shfl(h2v, 0);
            h2p1 = __shfl(h2v, 1);
            h2p2 = __shfl(h2v, 2);
            fence_lds();
            if (l == 0) cnts[W3DONE] = t + 1;
        }
    }
}

extern "C" void kernel_launch(void* const* d_in, const int* in_sizes, int n_in,
                              void* d_out, int out_size, void* d_ws, size_t ws_size,
                              hipStream_t stream)
{
    const float* x       = (const float*)d_in[0];
    const float* Wih0    = (const float*)d_in[1];
    const float* Whh0    = (const float*)d_in[2];
    const float* bih0    = (const float*)d_in[3];
    const float* bhh0    = (const float*)d_in[4];
    const float* Wih1    = (const float*)d_in[5];
    const float* Whh1    = (const float*)d_in[6];
    const float* bih1    = (const float*)d_in[7];
    const float* bhh1    = (const float*)d_in[8];
    const float* pre_h0  = (const float*)d_in[9];
    const float* pre_c0  = (const float*)d_in[10];
    const float* Wih2    = (const float*)d_in[11];
    const float* Whh2    = (const float*)d_in[12];
    const float* bih2    = (const float*)d_in[13];
    const float* bhh2    = (const float*)d_in[14];
    const float* post_h0 = (const float*)d_in[15];
    const float* post_c0 = (const float*)d_in[16];

    const int T = in_sizes[0];  // x is [T,1]

    lstm3_ring_kernel<<<dim3(1), dim3(256), 0, stream>>>(
        x, Wih0, Whh0, bih0, bhh0, Wih1, Whh1, bih1, bhh1, pre_h0, pre_c0,
        Wih2, Whh2, bih2, bhh2, post_h0, post_c0, (float*)d_out, T);
}

// Round 9
// 79296.674 us; speedup vs baseline: 1.1555x; 1.1555x over previous
//
#include <hip/hip_runtime.h>
#include <cstddef>

// ---------------------------------------------------------------------------
// 3-layer LSTM (1->32->32->3), T=200000 sequential steps.
// 4-wave systolic pipeline on one CU, one barrier per iteration (R5 base):
//   wave 0: layer 0           h0(t)                      at iter k = t
//   wave 1: layer 1 U-part    U(t)=Wih1*h0(t)            at iter k = t+1
//   wave 2: layer 1 V-part    V(t)=Whh1*h1(t-1); h1(t)   at iter k = t+2
//   wave 3: layer 2 + output  out(t)  (+ x prefetch)     at iter k = t+3
// Cross-stage values double-buffered in LDS by iteration parity.
// Barrier = raw s_barrier with lgkmcnt-only drain (stores fire-and-forget).
//
// R8: waves 0/2 lane relayout -- lane l owns cell l>>1, half l&1:
//   half 0 computes rows {cell, 64+cell}   = (i, g)
//   half 1 computes rows {32+cell, 96+cell} = (f, o)
// so the gate exchange is __shfl_xor(.,1) -> quad_perm DPP (VALU, ~8 cyc)
// instead of the cross-row DS shuffle (~50-60 cyc) of xor-32. Per-row
// arithmetic/summation order is bit-identical to R5; only the lane->row
// mapping changed. U reads hoisted before the V-dot in wave 2.
// ---------------------------------------------------------------------------

#define XCH 256  // x prefetch chunk (elements), power of two

typedef float f32x2 __attribute__((ext_vector_type(2)));

__device__ __forceinline__ f32x2 pk_fma(f32x2 a, f32x2 b, f32x2 c) {
    f32x2 d;
    asm("v_pk_fma_f32 %0, %1, %2, %3" : "=v"(d) : "v"(a), "v"(b), "v"(c));
    return d;
}
__device__ __forceinline__ f32x2 lds_ld2(const float* p) {
    f32x2 v; __builtin_memcpy(&v, p, sizeof(f32x2)); return v;
}

__device__ __forceinline__ float v_exp2(float x) {
    float r; asm("v_exp_f32 %0, %1" : "=v"(r) : "v"(x)); return r;
}
__device__ __forceinline__ float v_rcp(float x) {
    float r; asm("v_rcp_f32 %0, %1" : "=v"(r) : "v"(x)); return r;
}
// act = m / (1 + exp(z)) + a0, residual-compensated v_exp + Newton v_rcp.
__device__ __forceinline__ float fast_gate(float z, float m, float a0) {
    const float L2E    = 1.44269502162933349609375f;
    const float L2E_LO = 1.9259629911e-8f;
    const float LN2    = 0.69314718055994530942f;
    const float t  = z * L2E;
    const float r  = fmaf(z, L2E, -t);
    const float dt = fmaf(z, L2E_LO, r);
    const float e0 = v_exp2(t);
    const float e  = fmaf(e0, dt * LN2, e0);
    const float den = 1.0f + e;
    const float r0 = v_rcp(den);
    const float er = fmaf(-den, r0, 1.0f);
    const float r1 = fmaf(r0, er, r0);
    return fmaf(m, r1, a0);
}
__device__ __forceinline__ float fast_tanh(float c) {
    return fast_gate(-2.0f * c, 2.0f, -1.0f);
}

// neighbor exchange (lane ^ 1): lowers to quad_perm DPP (VALU), no DS pipe.
__device__ __forceinline__ float swap1(float v) {
    return __shfl_xor(v, 1);
}

// Workgroup barrier WITHOUT vmcnt drain.
__device__ __forceinline__ void pipe_barrier() {
    asm volatile("s_waitcnt lgkmcnt(0)\n\ts_barrier" ::: "memory");
}

__global__ __launch_bounds__(256, 1)
void lstm3_pipe6_kernel(const float* __restrict__ x,
                        const float* __restrict__ Wih0, const float* __restrict__ Whh0,
                        const float* __restrict__ bih0, const float* __restrict__ bhh0,
                        const float* __restrict__ Wih1, const float* __restrict__ Whh1,
                        const float* __restrict__ bih1, const float* __restrict__ bhh1,
                        const float* __restrict__ pre_h0, const float* __restrict__ pre_c0,
                        const float* __restrict__ Wih2, const float* __restrict__ Whh2,
                        const float* __restrict__ bih2, const float* __restrict__ bhh2,
                        const float* __restrict__ post_h0, const float* __restrict__ post_c0,
                        float* __restrict__ out, int T)
{
    const int tid = threadIdx.x;
    const int w   = tid >> 6;     // 0=L0, 1=L1-U, 2=L1-V, 3=L2+x
    const int l   = tid & 63;

    __shared__ __align__(16) float h0s[2][32];    // h0 double buffer
    __shared__ __align__(16) float h1s[2][32];    // h1 double buffer
    __shared__ __align__(16) float u1s[2][128];   // layer-1 U pre-activations
    __shared__ __align__(16) float xbuf[2][XCH];  // x chunk double buffer

    const int K = T + 3;          // pipeline depth 4 -> T+3 iterations

    if (w == 0) {
        // ===== wave 0: layer 0 (1 -> 32), t = k; xor-1 gate layout =====
        const int cell = l >> 1, hf = l & 1;
        const int rA = cell + (hf << 5);   // i-row | f-row
        const int rB = rA + 64;            // g-row | o-row
        const float wx0A = Wih0[rA];
        const float wx0B = Wih0[rB];
        const float b0A  = bih0[rA] + bhh0[rA];
        const float b0B  = bih0[rB] + bhh0[rB];
        f32x2 wA2[16], wB2[16];
#pragma unroll
        for (int r = 0; r < 16; ++r) {
            wA2[r][0] = Whh0[rA * 32 + 2 * r]; wA2[r][1] = Whh0[rA * 32 + 2 * r + 1];
            wB2[r][0] = Whh0[rB * 32 + 2 * r]; wB2[r][1] = Whh0[rB * 32 + 2 * r + 1];
        }
        const float kB  = (hf == 0) ? -2.0f : -1.0f;   // g: tanh | o: sigmoid
        const float mB  = (hf == 0) ?  2.0f :  1.0f;
        const float a0B = (hf == 0) ? -1.0f :  0.0f;

        float c0 = 0.0f;
        if (hf == 0) { c0 = pre_c0[cell]; h0s[1][cell] = pre_h0[cell]; }
        __syncthreads();

        for (int k = 0; k < K; ++k) {
            if (k < T) {
                const float xn = xbuf[(k >> 8) & 1][k & (XCH - 1)];
                const float* hp = h0s[(k + 1) & 1];   // h0(t-1)
                f32x2 aA0, aA1, aB0, aB1;
                aA0[0] = fmaf(xn, wx0A, b0A); aA0[1] = 0.0f;
                aA1[0] = 0.0f;                aA1[1] = 0.0f;
                aB0[0] = fmaf(xn, wx0B, b0B); aB0[1] = 0.0f;
                aB1[0] = 0.0f;                aB1[1] = 0.0f;
#pragma unroll
                for (int q = 0; q < 8; ++q) {
                    const f32x2 h01 = lds_ld2(&hp[q * 4]);
                    const f32x2 h23 = lds_ld2(&hp[q * 4 + 2]);
                    aA0 = pk_fma(h01, wA2[2 * q],     aA0);
                    aA1 = pk_fma(h23, wA2[2 * q + 1], aA1);
                    aB0 = pk_fma(h01, wB2[2 * q],     aB0);
                    aB1 = pk_fma(h23, wB2[2 * q + 1], aB1);
                }
                const float sA = (aA0[0] + aA0[1]) + (aA1[0] + aA1[1]);
                const float sB = (aB0[0] + aB0[1]) + (aB1[0] + aB1[1]);
                const float actA = fast_gate(-sA, 1.0f, 0.0f);    // i | f
                const float actB = fast_gate(kB * sB, mB, a0B);   // g | o
                const float foA = swap1(actA);    // hf=0 lanes: f
                const float foB = swap1(actB);    // hf=0 lanes: o
                if (hf == 0) {
                    c0 = fmaf(foA, c0, actA * actB);
                    h0s[k & 1][cell] = foB * fast_tanh(c0);
                }
            }
            pipe_barrier();
        }
    } else if (w == 1) {
        // ========= wave 1: layer 1 U = Wih1 * h0(t), t = k-1 =========
        // (row order unchanged: ur[row] = U[row], rows l and l+64)
        const int gA = l, gB = l + 64;
        const float b1A = bih1[gA] + bhh1[gA];
        f32x2 wA2[16], wB2[16];
#pragma unroll
        for (int r = 0; r < 16; ++r) {
            wA2[r][0] = Wih1[gA * 32 + 2 * r]; wA2[r][1] = Wih1[gA * 32 + 2 * r + 1];
            wB2[r][0] = Wih1[gB * 32 + 2 * r]; wB2[r][1] = Wih1[gB * 32 + 2 * r + 1];
        }
        __syncthreads();

        for (int k = 0; k < K; ++k) {
            if (k >= 1 && k <= T) {
                const float* hp = h0s[(k - 1) & 1];   // h0(t)
                f32x2 uA0, uA1, uB0, uB1;
                uA0[0] = b1A;  uA0[1] = 0.0f;
                uA1[0] = 0.0f; uA1[1] = 0.0f;
                uB0[0] = 0.0f; uB0[1] = 0.0f;
                uB1[0] = 0.0f; uB1[1] = 0.0f;
#pragma unroll
                for (int q = 0; q < 8; ++q) {
                    const f32x2 h01 = lds_ld2(&hp[q * 4]);
                    const f32x2 h23 = lds_ld2(&hp[q * 4 + 2]);
                    uA0 = pk_fma(h01, wA2[2 * q],     uA0);
                    uA1 = pk_fma(h23, wA2[2 * q + 1], uA1);
                    uB0 = pk_fma(h01, wB2[2 * q],     uB0);
                    uB1 = pk_fma(h23, wB2[2 * q + 1], uB1);
                }
                u1s[k & 1][l]      = (uA0[0] + uA0[1]) + (uA1[0] + uA1[1]);
                u1s[k & 1][l + 64] = (uB0[0] + uB0[1]) + (uB1[0] + uB1[1]);
            }
            pipe_barrier();
        }
    } else if (w == 2) {
        // ===== wave 2: layer 1 V + cell, t = k-2; xor-1 gate layout =====
        const int cell = l >> 1, hf = l & 1;
        const int rA = cell + (hf << 5);
        const int rB = rA + 64;
        const float b1B = bih1[rB] + bhh1[rB];
        f32x2 wA2[16], wB2[16];
#pragma unroll
        for (int r = 0; r < 16; ++r) {
            wA2[r][0] = Whh1[rA * 32 + 2 * r]; wA2[r][1] = Whh1[rA * 32 + 2 * r + 1];
            wB2[r][0] = Whh1[rB * 32 + 2 * r]; wB2[r][1] = Whh1[rB * 32 + 2 * r + 1];
        }
        const float kB  = (hf == 0) ? -2.0f : -1.0f;
        const float mB  = (hf == 0) ?  2.0f :  1.0f;
        const float a0B = (hf == 0) ? -1.0f :  0.0f;

        float c1 = 0.0f;
        if (hf == 0) { c1 = pre_c0[32 + cell]; h1s[1][cell] = pre_h0[32 + cell]; }
        __syncthreads();

        for (int k = 0; k < K; ++k) {
            if (k >= 2 && k <= T + 1) {
                const float* up = u1s[(k - 1) & 1];
                const float UA = up[rA];              // issue early
                const float UB = up[rB];
                const float* gp = h1s[(k - 1) & 1];   // h1(t-1)
                f32x2 vA0, vA1, vB0, vB1;
                vA0[0] = 0.0f; vA0[1] = 0.0f;
                vA1[0] = 0.0f; vA1[1] = 0.0f;
                vB0[0] = b1B;  vB0[1] = 0.0f;
                vB1[0] = 0.0f; vB1[1] = 0.0f;
#pragma unroll
                for (int q = 0; q < 8; ++q) {
                    const f32x2 g01 = lds_ld2(&gp[q * 4]);
                    const f32x2 g23 = lds_ld2(&gp[q * 4 + 2]);
                    vA0 = pk_fma(g01, wA2[2 * q],     vA0);
                    vA1 = pk_fma(g23, wA2[2 * q + 1], vA1);
                    vB0 = pk_fma(g01, wB2[2 * q],     vB0);
                    vB1 = pk_fma(g23, wB2[2 * q + 1], vB1);
                }
                const float sA = UA + ((vA0[0] + vA0[1]) + (vA1[0] + vA1[1]));
                const float sB = UB + ((vB0[0] + vB0[1]) + (vB1[0] + vB1[1]));
                const float actA = fast_gate(-sA, 1.0f, 0.0f);
                const float actB = fast_gate(kB * sB, mB, a0B);
                const float foA = swap1(actA);
                const float foB = swap1(actB);
                if (hf == 0) {
                    c1 = fmaf(foA, c1, actA * actB);
                    h1s[k & 1][cell] = foB * fast_tanh(c1);
                }
            }
            pipe_barrier();
        }
    } else {
        // ===== wave 3: layer 2 (32 -> 3) + output, t = k-3; x prefetch =====
        const int g2 = (l < 48) ? (l >> 2) : 0;
        const int p  = l & 3;
        f32x2 w2p[4];
#pragma unroll
        for (int r = 0; r < 4; ++r) {
            w2p[r][0] = Wih2[g2 * 32 + p * 8 + 2 * r];
            w2p[r][1] = Wih2[g2 * 32 + p * 8 + 2 * r + 1];
        }
        float wr2[3];
#pragma unroll
        for (int r = 0; r < 3; ++r) wr2[r] = Whh2[g2 * 3 + r];
        const float b2 = bih2[g2] + bhh2[g2];
        const bool  g2tanh = (g2 >= 6 && g2 <= 8);
        const float k2  = g2tanh ? -2.0f : -1.0f;
        const float m2  = g2tanh ?  2.0f :  1.0f;
        const float a02 = g2tanh ? -1.0f :  0.0f;

        float c2 = 0.0f;
        if (l < 3) c2 = post_c0[l];
        float h2p0 = post_h0[0], h2p1 = post_h0[1], h2p2 = post_h0[2];
        float h2v = 0.0f;

        // preload x chunk 0
        {
            const int i0 = 4 * l;
            if (i0 < T) {
                const float* xp = x + i0;
                float4 v;
                v.x = xp[0] / 25.0f;
                v.y = (i0 + 1 < T) ? xp[1] / 25.0f : 0.0f;
                v.z = (i0 + 2 < T) ? xp[2] / 25.0f : 0.0f;
                v.w = (i0 + 3 < T) ? xp[3] / 25.0f : 0.0f;
                __builtin_memcpy(&xbuf[0][i0], &v, sizeof(float4));
            }
        }
        __syncthreads();

        for (int k = 0; k < K; ++k) {
            if (k < T && (k & (XCH - 1)) == 0) {
                const int c = (k >> 8) + 1;
                const int base = c * XCH;
                const int i0 = base + 4 * l;
                if (base < T && i0 < T) {
                    const float* xp = x + i0;
                    float4 v;
                    v.x = xp[0] / 25.0f;
                    v.y = (i0 + 1 < T) ? xp[1] / 25.0f : 0.0f;
                    v.z = (i0 + 2 < T) ? xp[2] / 25.0f : 0.0f;
                    v.w = (i0 + 3 < T) ? xp[3] / 25.0f : 0.0f;
                    __builtin_memcpy(&xbuf[c & 1][4 * l], &v, sizeof(float4));
                }
            }
            if (k >= 3) {
                const int t = k - 3;
                const float* hp = h1s[(k - 1) & 1];   // h1(t)
                f32x2 acc; acc[0] = 0.0f; acc[1] = 0.0f;
                {
                    const f32x2 a01 = lds_ld2(&hp[p * 8 + 0]);
                    const f32x2 a23 = lds_ld2(&hp[p * 8 + 2]);
                    const f32x2 b01 = lds_ld2(&hp[p * 8 + 4]);
                    const f32x2 b23 = lds_ld2(&hp[p * 8 + 6]);
                    acc = pk_fma(a01, w2p[0], acc);
                    acc = pk_fma(a23, w2p[1], acc);
                    acc = pk_fma(b01, w2p[2], acc);
                    acc = pk_fma(b23, w2p[3], acc);
                }
                float a2 = acc[0] + acc[1];
                a2 += __shfl_xor(a2, 1);
                a2 += __shfl_xor(a2, 2);
                const float rec = fmaf(wr2[2], h2p2,
                                  fmaf(wr2[1], h2p1,
                                  fmaf(wr2[0], h2p0, b2)));
                a2 += rec;
                const float act2 = fast_gate(k2 * a2, m2, a02);
                const int j = (l < 3) ? l : 0;
                const float i2  = __shfl(act2,  4 * j);
                const float f2  = __shfl(act2, 12 + 4 * j);
                const float g2v = __shfl(act2, 24 + 4 * j);
                const float o2  = __shfl(act2, 36 + 4 * j);
                if (l < 3) {
                    c2 = fmaf(f2, c2, i2 * g2v);
                    h2v = o2 * fast_tanh(c2);
                    out[(size_t)t * 3 + l] = h2v;   // fire-and-forget
                }
                h2p0 = __shfl(h2v, 0);
                h2p1 = __shfl(h2v, 1);
                h2p2 = __shfl(h2v, 2);
            }
            pipe_barrier();
        }
    }
}

extern "C" void kernel_launch(void* const* d_in, const int* in_sizes, int n_in,
                              void* d_out, int out_size, void* d_ws, size_t ws_size,
                              hipStream_t stream)
{
    const float* x       = (const float*)d_in[0];
    const float* Wih0    = (const float*)d_in[1];
    const float* Whh0    = (const float*)d_in[2];
    const float* bih0    = (const float*)d_in[3];
    const float* bhh0    = (const float*)d_in[4];
    const float* Wih1    = (const float*)d_in[5];
    const float* Whh1    = (const float*)d_in[6];
    const float* bih1    = (const float*)d_in[7];
    const float* bhh1    = (const float*)d_in[8];
    const float* pre_h0  = (const float*)d_in[9];
    const float* pre_c0  = (const float*)d_in[10];
    const float* Wih2    = (const float*)d_in[11];
    const float* Whh2    = (const float*)d_in[12];
    const float* bih2    = (const float*)d_in[13];
    const float* bhh2    = (const float*)d_in[14];
    const float* post_h0 = (const float*)d_in[15];
    const float* post_c0 = (const float*)d_in[16];

    const int T = in_sizes[0];  // x is [T,1]

    lstm3_pipe6_kernel<<<dim3(1), dim3(256), 0, stream>>>(
        x, Wih0, Whh0, bih0, bhh0, Wih1, Whh1, bih1, bhh1, pre_h0, pre_c0,
        Wih2, Whh2, bih2, bhh2, post_h0, post_c0, (float*)d_out, T);
}

// Round 10
// 75754.871 us; speedup vs baseline: 1.2095x; 1.0468x over previous
//
#include <hip/hip_runtime.h>
#include <cstddef>

// ---------------------------------------------------------------------------
// 3-layer LSTM (1->32->32->3), T=200000 sequential steps.
// 4-wave systolic pipeline on one CU, FOUR timesteps per barrier epoch:
//   wave 0: layer 0           h0(4e..4e+3)        (self-recurrent, fenced)
//   wave 1: layer 1 U-part    U(4(e-1)+j), j=0..3 (no intra-epoch deps, ILP)
//   wave 2: layer 1 V + cell  h1(4(e-2)+j)        (self-recurrent, fenced)
//   wave 3: layer 2 + output  out(4(e-3)+j) + x chunk staging
// Cross-stage values in [epoch-parity][step 0..3] LDS buffers; ONE s_barrier
// per epoch (lgkmcnt-only drain; global stores fire-and-forget). Intra-epoch
// self-dependencies use s_waitcnt lgkmcnt(0) fences (same-wave write->read).
// R8's xor-1 gate layout (DPP exchange) and bit-identical arithmetic.
// ---------------------------------------------------------------------------

#define XCH 256  // x chunk elements (power of two)

typedef float f32x2 __attribute__((ext_vector_type(2)));

__device__ __forceinline__ f32x2 pk_fma(f32x2 a, f32x2 b, f32x2 c) {
    f32x2 d;
    asm("v_pk_fma_f32 %0, %1, %2, %3" : "=v"(d) : "v"(a), "v"(b), "v"(c));
    return d;
}
__device__ __forceinline__ f32x2 lds_ld2(const float* p) {
    f32x2 v; __builtin_memcpy(&v, p, sizeof(f32x2)); return v;
}

__device__ __forceinline__ float v_exp2(float x) {
    float r; asm("v_exp_f32 %0, %1" : "=v"(r) : "v"(x)); return r;
}
__device__ __forceinline__ float v_rcp(float x) {
    float r; asm("v_rcp_f32 %0, %1" : "=v"(r) : "v"(x)); return r;
}
// act = m / (1 + exp(z)) + a0, residual-compensated v_exp + Newton v_rcp.
__device__ __forceinline__ float fast_gate(float z, float m, float a0) {
    const float L2E    = 1.44269502162933349609375f;
    const float L2E_LO = 1.9259629911e-8f;
    const float LN2    = 0.69314718055994530942f;
    const float t  = z * L2E;
    const float r  = fmaf(z, L2E, -t);
    const float dt = fmaf(z, L2E_LO, r);
    const float e0 = v_exp2(t);
    const float e  = fmaf(e0, dt * LN2, e0);
    const float den = 1.0f + e;
    const float r0 = v_rcp(den);
    const float er = fmaf(-den, r0, 1.0f);
    const float r1 = fmaf(r0, er, r0);
    return fmaf(m, r1, a0);
}
__device__ __forceinline__ float fast_tanh(float c) {
    return fast_gate(-2.0f * c, 2.0f, -1.0f);
}

// neighbor exchange (lane ^ 1): quad_perm DPP (VALU), no DS pipe.
__device__ __forceinline__ float swap1(float v) {
    return __shfl_xor(v, 1);
}

// drain own LDS ops (same-wave write->read ordering), compiler fence
__device__ __forceinline__ void fence_lds() {
    asm volatile("s_waitcnt lgkmcnt(0)" ::: "memory");
}
// epoch barrier WITHOUT vmcnt drain
__device__ __forceinline__ void pipe_barrier() {
    asm volatile("s_waitcnt lgkmcnt(0)\n\ts_barrier" ::: "memory");
}

__global__ __launch_bounds__(256, 1)
void lstm3_epoch_kernel(const float* __restrict__ x,
                        const float* __restrict__ Wih0, const float* __restrict__ Whh0,
                        const float* __restrict__ bih0, const float* __restrict__ bhh0,
                        const float* __restrict__ Wih1, const float* __restrict__ Whh1,
                        const float* __restrict__ bih1, const float* __restrict__ bhh1,
                        const float* __restrict__ pre_h0, const float* __restrict__ pre_c0,
                        const float* __restrict__ Wih2, const float* __restrict__ Whh2,
                        const float* __restrict__ bih2, const float* __restrict__ bhh2,
                        const float* __restrict__ post_h0, const float* __restrict__ post_c0,
                        float* __restrict__ out, int T)
{
    const int tid = threadIdx.x;
    const int w   = tid >> 6;     // 0=L0, 1=L1-U, 2=L1-V, 3=L2+x
    const int l   = tid & 63;

    __shared__ __align__(16) float h0s[2][4][32];    // [parity][step][cell]
    __shared__ __align__(16) float h1s[2][4][32];
    __shared__ __align__(16) float u1s[2][4][128];   // [parity][step][row]
    __shared__ __align__(16) float xbuf[2][XCH];

    const int T4   = (T + 3) >> 2;
    const int Etot = T4 + 3;

    if (w == 0) {
        // ===== wave 0: layer 0 (1 -> 32); xor-1 gate layout =====
        const int cell = l >> 1, hf = l & 1;
        const int rA = cell + (hf << 5);   // i-row | f-row
        const int rB = rA + 64;            // g-row | o-row
        const float wx0A = Wih0[rA];
        const float wx0B = Wih0[rB];
        const float b0A  = bih0[rA] + bhh0[rA];
        const float b0B  = bih0[rB] + bhh0[rB];
        f32x2 wA2[16], wB2[16];
#pragma unroll
        for (int r = 0; r < 16; ++r) {
            wA2[r][0] = Whh0[rA * 32 + 2 * r]; wA2[r][1] = Whh0[rA * 32 + 2 * r + 1];
            wB2[r][0] = Whh0[rB * 32 + 2 * r]; wB2[r][1] = Whh0[rB * 32 + 2 * r + 1];
        }
        const float kB  = (hf == 0) ? -2.0f : -1.0f;
        const float mB  = (hf == 0) ?  2.0f :  1.0f;
        const float a0B = (hf == 0) ? -1.0f :  0.0f;

        float c0 = 0.0f;
        if (hf == 0) { c0 = pre_c0[cell]; h0s[1][3][cell] = pre_h0[cell]; }
        __syncthreads();

        for (int e = 0; e < Etot; ++e) {
#pragma unroll
            for (int j = 0; j < 4; ++j) {
                const int t = 4 * e + j;
                if (t < T) {
                    const float xn = xbuf[(t >> 8) & 1][t & (XCH - 1)];
                    const float* hp = (j == 0) ? h0s[(e + 1) & 1][3]
                                               : h0s[e & 1][j - 1];
                    f32x2 aA0, aA1, aB0, aB1;
                    aA0[0] = fmaf(xn, wx0A, b0A); aA0[1] = 0.0f;
                    aA1[0] = 0.0f;                aA1[1] = 0.0f;
                    aB0[0] = fmaf(xn, wx0B, b0B); aB0[1] = 0.0f;
                    aB1[0] = 0.0f;                aB1[1] = 0.0f;
#pragma unroll
                    for (int q = 0; q < 8; ++q) {
                        const f32x2 h01 = lds_ld2(&hp[q * 4]);
                        const f32x2 h23 = lds_ld2(&hp[q * 4 + 2]);
                        aA0 = pk_fma(h01, wA2[2 * q],     aA0);
                        aA1 = pk_fma(h23, wA2[2 * q + 1], aA1);
                        aB0 = pk_fma(h01, wB2[2 * q],     aB0);
                        aB1 = pk_fma(h23, wB2[2 * q + 1], aB1);
                    }
                    const float sA = (aA0[0] + aA0[1]) + (aA1[0] + aA1[1]);
                    const float sB = (aB0[0] + aB0[1]) + (aB1[0] + aB1[1]);
                    const float actA = fast_gate(-sA, 1.0f, 0.0f);
                    const float actB = fast_gate(kB * sB, mB, a0B);
                    const float foA = swap1(actA);
                    const float foB = swap1(actB);
                    if (hf == 0) {
                        c0 = fmaf(foA, c0, actA * actB);
                        h0s[e & 1][j][cell] = foB * fast_tanh(c0);
                    }
                    if (j < 3) fence_lds();
                }
            }
            pipe_barrier();
        }
    } else if (w == 1) {
        // ===== wave 1: layer 1 U = Wih1 * h0 (4 independent dots) =====
        const int gA = l, gB = l + 64;
        const float b1A = bih1[gA] + bhh1[gA];
        f32x2 wA2[16], wB2[16];
#pragma unroll
        for (int r = 0; r < 16; ++r) {
            wA2[r][0] = Wih1[gA * 32 + 2 * r]; wA2[r][1] = Wih1[gA * 32 + 2 * r + 1];
            wB2[r][0] = Wih1[gB * 32 + 2 * r]; wB2[r][1] = Wih1[gB * 32 + 2 * r + 1];
        }
        __syncthreads();

        for (int e = 0; e < Etot; ++e) {
            if (e >= 1) {
#pragma unroll
                for (int j = 0; j < 4; ++j) {
                    const int t = 4 * (e - 1) + j;
                    if (t < T) {
                        const float* hp = h0s[(e - 1) & 1][j];
                        f32x2 uA0, uA1, uB0, uB1;
                        uA0[0] = b1A;  uA0[1] = 0.0f;
                        uA1[0] = 0.0f; uA1[1] = 0.0f;
                        uB0[0] = 0.0f; uB0[1] = 0.0f;
                        uB1[0] = 0.0f; uB1[1] = 0.0f;
#pragma unroll
                        for (int q = 0; q < 8; ++q) {
                            const f32x2 h01 = lds_ld2(&hp[q * 4]);
                            const f32x2 h23 = lds_ld2(&hp[q * 4 + 2]);
                            uA0 = pk_fma(h01, wA2[2 * q],     uA0);
                            uA1 = pk_fma(h23, wA2[2 * q + 1], uA1);
                            uB0 = pk_fma(h01, wB2[2 * q],     uB0);
                            uB1 = pk_fma(h23, wB2[2 * q + 1], uB1);
                        }
                        u1s[e & 1][j][l]      = (uA0[0] + uA0[1]) + (uA1[0] + uA1[1]);
                        u1s[e & 1][j][l + 64] = (uB0[0] + uB0[1]) + (uB1[0] + uB1[1]);
                    }
                }
            }
            pipe_barrier();
        }
    } else if (w == 2) {
        // ===== wave 2: layer 1 V + cell; xor-1 gate layout =====
        const int cell = l >> 1, hf = l & 1;
        const int rA = cell + (hf << 5);
        const int rB = rA + 64;
        const float b1B = bih1[rB] + bhh1[rB];
        f32x2 wA2[16], wB2[16];
#pragma unroll
        for (int r = 0; r < 16; ++r) {
            wA2[r][0] = Whh1[rA * 32 + 2 * r]; wA2[r][1] = Whh1[rA * 32 + 2 * r + 1];
            wB2[r][0] = Whh1[rB * 32 + 2 * r]; wB2[r][1] = Whh1[rB * 32 + 2 * r + 1];
        }
        const float kB  = (hf == 0) ? -2.0f : -1.0f;
        const float mB  = (hf == 0) ?  2.0f :  1.0f;
        const float a0B = (hf == 0) ? -1.0f :  0.0f;

        float c1 = 0.0f;
        if (hf == 0) { c1 = pre_c0[32 + cell]; h1s[1][3][cell] = pre_h0[32 + cell]; }
        __syncthreads();

        for (int e = 0; e < Etot; ++e) {
            if (e >= 2) {
#pragma unroll
                for (int j = 0; j < 4; ++j) {
                    const int t = 4 * (e - 2) + j;
                    if (t < T) {
                        const float* up = u1s[(e - 1) & 1][j];
                        const float UA = up[rA];              // issue early
                        const float UB = up[rB];
                        const float* gp = (j == 0) ? h1s[(e + 1) & 1][3]
                                                   : h1s[e & 1][j - 1];
                        f32x2 vA0, vA1, vB0, vB1;
                        vA0[0] = 0.0f; vA0[1] = 0.0f;
                        vA1[0] = 0.0f; vA1[1] = 0.0f;
                        vB0[0] = b1B;  vB0[1] = 0.0f;
                        vB1[0] = 0.0f; vB1[1] = 0.0f;
#pragma unroll
                        for (int q = 0; q < 8; ++q) {
                            const f32x2 g01 = lds_ld2(&gp[q * 4]);
                            const f32x2 g23 = lds_ld2(&gp[q * 4 + 2]);
                            vA0 = pk_fma(g01, wA2[2 * q],     vA0);
                            vA1 = pk_fma(g23, wA2[2 * q + 1], vA1);
                            vB0 = pk_fma(g01, wB2[2 * q],     vB0);
                            vB1 = pk_fma(g23, wB2[2 * q + 1], vB1);
                        }
                        const float sA = UA + ((vA0[0] + vA0[1]) + (vA1[0] + vA1[1]));
                        const float sB = UB + ((vB0[0] + vB0[1]) + (vB1[0] + vB1[1]));
                        const float actA = fast_gate(-sA, 1.0f, 0.0f);
                        const float actB = fast_gate(kB * sB, mB, a0B);
                        const float foA = swap1(actA);
                        const float foB = swap1(actB);
                        if (hf == 0) {
                            c1 = fmaf(foA, c1, actA * actB);
                            h1s[e & 1][j][cell] = foB * fast_tanh(c1);
                        }
                        if (j < 3) fence_lds();
                    }
                }
            }
            pipe_barrier();
        }
    } else {
        // ===== wave 3: layer 2 (32 -> 3) + output; x chunk staging =====
        const int g2 = (l < 48) ? (l >> 2) : 0;
        const int p  = l & 3;
        f32x2 w2p[4];
#pragma unroll
        for (int r = 0; r < 4; ++r) {
            w2p[r][0] = Wih2[g2 * 32 + p * 8 + 2 * r];
            w2p[r][1] = Wih2[g2 * 32 + p * 8 + 2 * r + 1];
        }
        float wr2[3];
#pragma unroll
        for (int r = 0; r < 3; ++r) wr2[r] = Whh2[g2 * 3 + r];
        const float b2 = bih2[g2] + bhh2[g2];
        const bool  g2tanh = (g2 >= 6 && g2 <= 8);
        const float k2  = g2tanh ? -2.0f : -1.0f;
        const float m2  = g2tanh ?  2.0f :  1.0f;
        const float a02 = g2tanh ? -1.0f :  0.0f;

        float c2 = 0.0f;
        if (l < 3) c2 = post_c0[l];
        float h2p0 = post_h0[0], h2p1 = post_h0[1], h2p2 = post_h0[2];
        float h2v = 0.0f;

        // stage x chunk 0
        {
            const int i0 = 4 * l;
            if (i0 < T) {
                const float* xp = x + i0;
                float4 v;
                v.x = xp[0] / 25.0f;
                v.y = (i0 + 1 < T) ? xp[1] / 25.0f : 0.0f;
                v.z = (i0 + 2 < T) ? xp[2] / 25.0f : 0.0f;
                v.w = (i0 + 3 < T) ? xp[3] / 25.0f : 0.0f;
                __builtin_memcpy(&xbuf[0][i0], &v, sizeof(float4));
            }
        }
        __syncthreads();

        for (int e = 0; e < Etot; ++e) {
            // stage next chunk once per 64 epochs (256 steps)
            if ((e & 63) == 0) {
                const int c = (e >> 6) + 1;
                const int base = c * XCH;
                if (base < T) {
                    const int i0 = base + 4 * l;
                    if (i0 < T) {
                        const float* xp = x + i0;
                        float4 v;
                        v.x = xp[0] / 25.0f;
                        v.y = (i0 + 1 < T) ? xp[1] / 25.0f : 0.0f;
                        v.z = (i0 + 2 < T) ? xp[2] / 25.0f : 0.0f;
                        v.w = (i0 + 3 < T) ? xp[3] / 25.0f : 0.0f;
                        __builtin_memcpy(&xbuf[c & 1][4 * l], &v, sizeof(float4));
                    }
                }
            }
            if (e >= 3) {
#pragma unroll
                for (int j = 0; j < 4; ++j) {
                    const int t = 4 * (e - 3) + j;
                    if (t < T) {
                        const float* hp = h1s[(e - 1) & 1][j];
                        f32x2 acc; acc[0] = 0.0f; acc[1] = 0.0f;
                        {
                            const f32x2 a01 = lds_ld2(&hp[p * 8 + 0]);
                            const f32x2 a23 = lds_ld2(&hp[p * 8 + 2]);
                            const f32x2 b01 = lds_ld2(&hp[p * 8 + 4]);
                            const f32x2 b23 = lds_ld2(&hp[p * 8 + 6]);
                            acc = pk_fma(a01, w2p[0], acc);
                            acc = pk_fma(a23, w2p[1], acc);
                            acc = pk_fma(b01, w2p[2], acc);
                            acc = pk_fma(b23, w2p[3], acc);
                        }
                        float a2 = acc[0] + acc[1];
                        a2 += __shfl_xor(a2, 1);
                        a2 += __shfl_xor(a2, 2);
                        const float rec = fmaf(wr2[2], h2p2,
                                          fmaf(wr2[1], h2p1,
                                          fmaf(wr2[0], h2p0, b2)));
                        a2 += rec;
                        const float act2 = fast_gate(k2 * a2, m2, a02);
                        const int lj = (l < 3) ? l : 0;
                        const float i2  = __shfl(act2,  4 * lj);
                        const float f2  = __shfl(act2, 12 + 4 * lj);
                        const float g2v = __shfl(act2, 24 + 4 * lj);
                        const float o2  = __shfl(act2, 36 + 4 * lj);
                        if (l < 3) {
                            c2 = fmaf(f2, c2, i2 * g2v);
                            h2v = o2 * fast_tanh(c2);
                            out[(size_t)t * 3 + l] = h2v;   // fire-and-forget
                        }
                        h2p0 = __shfl(h2v, 0);
                        h2p1 = __shfl(h2v, 1);
                        h2p2 = __shfl(h2v, 2);
                    }
                }
            }
            pipe_barrier();
        }
    }
}

extern "C" void kernel_launch(void* const* d_in, const int* in_sizes, int n_in,
                              void* d_out, int out_size, void* d_ws, size_t ws_size,
                              hipStream_t stream)
{
    const float* x       = (const float*)d_in[0];
    const float* Wih0    = (const float*)d_in[1];
    const float* Whh0    = (const float*)d_in[2];
    const float* bih0    = (const float*)d_in[3];
    const float* bhh0    = (const float*)d_in[4];
    const float* Wih1    = (const float*)d_in[5];
    const float* Whh1    = (const float*)d_in[6];
    const float* bih1    = (const float*)d_in[7];
    const float* bhh1    = (const float*)d_in[8];
    const float* pre_h0  = (const float*)d_in[9];
    const float* pre_c0  = (const float*)d_in[10];
    const float* Wih2    = (const float*)d_in[11];
    const float* Whh2    = (const float*)d_in[12];
    const float* bih2    = (const float*)d_in[13];
    const float* bhh2    = (const float*)d_in[14];
    const float* post_h0 = (const float*)d_in[15];
    const float* post_c0 = (const float*)d_in[16];

    const int T = in_sizes[0];  // x is [T,1]

    lstm3_epoch_kernel<<<dim3(1), dim3(256), 0, stream>>>(
        x, Wih0, Whh0, bih0, bhh0, Wih1, Whh1, bih1, bhh1, pre_h0, pre_c0,
        Wih2, Whh2, bih2, bhh2, post_h0, post_c0, (float*)d_out, T);
}